// Round 1
// baseline (3320.260 us; speedup 1.0000x reference)
//
#include <hip/hip_runtime.h>
#include <hip/hip_bf16.h>
#include <math.h>

// Problem constants
#define B_SZ    4
#define S_LEN   4096
#define DMODEL  1024
#define NH      16
#define KDIM    64
#define NF      256
#define NROWS   (B_SZ * S_LEN)          // 16384
#define RFF_SCALE 0.08838834764831845f  // sqrt(2/256)
#define NORM_Q    0.125f                // 1/sqrt(64)

// ---------------------------------------------------------------------------
// Generic fp32 GEMM: C[M,N] = A[M,K] @ B[K,N] + bias[N]
// 128x128 tile, BK=16, 256 threads, 8x8 per thread.
// ---------------------------------------------------------------------------
__global__ __launch_bounds__(256) void gemm_bias_f32(
    const float* __restrict__ A, const float* __restrict__ Bm,
    const float* __restrict__ bias, float* __restrict__ C,
    int M, int N, int K)
{
  __shared__ float As[16][132];   // transposed A tile: As[k][m]
  __shared__ float Bs[16][132];   // Bs[k][n]
  const int tid = threadIdx.x;
  const int m0 = blockIdx.y * 128;
  const int n0 = blockIdx.x * 128;
  const int tx = tid & 15;        // n-subtile
  const int ty = tid >> 4;        // m-subtile
  float acc[8][8];
#pragma unroll
  for (int i = 0; i < 8; ++i)
#pragma unroll
    for (int j = 0; j < 8; ++j) acc[i][j] = 0.f;

  for (int k0 = 0; k0 < K; k0 += 16) {
#pragma unroll
    for (int i = 0; i < 8; ++i) {
      int e = tid + i * 256;          // 0..2047
      int r = e >> 4, kk = e & 15;
      As[kk][r] = A[(size_t)(m0 + r) * K + k0 + kk];
    }
#pragma unroll
    for (int i = 0; i < 8; ++i) {
      int e = tid + i * 256;
      int kk = e >> 7, n = e & 127;
      Bs[kk][n] = Bm[(size_t)(k0 + kk) * N + n0 + n];
    }
    __syncthreads();
#pragma unroll
    for (int kk = 0; kk < 16; ++kk) {
      float4 a0 = *(const float4*)&As[kk][ty * 8];
      float4 a1 = *(const float4*)&As[kk][ty * 8 + 4];
      float4 b0 = *(const float4*)&Bs[kk][tx * 8];
      float4 b1 = *(const float4*)&Bs[kk][tx * 8 + 4];
      float a[8] = {a0.x, a0.y, a0.z, a0.w, a1.x, a1.y, a1.z, a1.w};
      float b[8] = {b0.x, b0.y, b0.z, b0.w, b1.x, b1.y, b1.z, b1.w};
#pragma unroll
      for (int i = 0; i < 8; ++i)
#pragma unroll
        for (int j = 0; j < 8; ++j)
          acc[i][j] = fmaf(a[i], b[j], acc[i][j]);
    }
    __syncthreads();
  }
#pragma unroll
  for (int i = 0; i < 8; ++i) {
    size_t row = (size_t)(m0 + ty * 8 + i) * N + n0 + tx * 8;
    float4 o0, o1;
    o0.x = acc[i][0] + bias[n0 + tx * 8 + 0];
    o0.y = acc[i][1] + bias[n0 + tx * 8 + 1];
    o0.z = acc[i][2] + bias[n0 + tx * 8 + 2];
    o0.w = acc[i][3] + bias[n0 + tx * 8 + 3];
    o1.x = acc[i][4] + bias[n0 + tx * 8 + 4];
    o1.y = acc[i][5] + bias[n0 + tx * 8 + 5];
    o1.z = acc[i][6] + bias[n0 + tx * 8 + 6];
    o1.w = acc[i][7] + bias[n0 + tx * 8 + 7];
    *(float4*)&C[row]     = o0;
    *(float4*)&C[row + 4] = o1;
  }
}

// ---------------------------------------------------------------------------
// RFF tile: given transposed input tile Xt[d][row] (64x64), compute
// x' = cos(0.125 * (x @ rffW) + rffb) * sqrt(2/F) into xps[row][f] (64x256).
// Thread map: tx = tid&31 -> 8 features, ty = tid>>5 -> 8 rows.
// ---------------------------------------------------------------------------
__device__ __forceinline__ void rff_tile(
    const float (*Xt)[68], float (*xps)[268],
    const float* __restrict__ rffW, const float* __restrict__ rffb, int tid)
{
  const int tx = tid & 31;
  const int ty = tid >> 5;
  const int f0 = tx * 8;
  float pacc[8][8];
#pragma unroll
  for (int i = 0; i < 8; ++i)
#pragma unroll
    for (int j = 0; j < 8; ++j) pacc[i][j] = 0.f;

  for (int d = 0; d < 64; ++d) {
    float4 a0 = *(const float4*)&Xt[d][ty * 8];
    float4 a1 = *(const float4*)&Xt[d][ty * 8 + 4];
    float4 w0 = *(const float4*)&rffW[d * NF + f0];
    float4 w1 = *(const float4*)&rffW[d * NF + f0 + 4];
    float a[8] = {a0.x, a0.y, a0.z, a0.w, a1.x, a1.y, a1.z, a1.w};
    float w[8] = {w0.x, w0.y, w0.z, w0.w, w1.x, w1.y, w1.z, w1.w};
#pragma unroll
    for (int i = 0; i < 8; ++i)
#pragma unroll
      for (int j = 0; j < 8; ++j)
        pacc[i][j] = fmaf(a[i], w[j], pacc[i][j]);
  }
  float bfv[8];
#pragma unroll
  for (int j = 0; j < 8; ++j) bfv[j] = rffb[f0 + j];
#pragma unroll
  for (int i = 0; i < 8; ++i) {
    float c[8];
#pragma unroll
    for (int j = 0; j < 8; ++j) {
      float p = fmaf(NORM_Q, pacc[i][j], bfv[j]);
      c[j] = __cosf(p) * RFF_SCALE;
    }
    float4 o0 = {c[0], c[1], c[2], c[3]};
    float4 o1 = {c[4], c[5], c[6], c[7]};
    *(float4*)&xps[ty * 8 + i][f0]     = o0;
    *(float4*)&xps[ty * 8 + i][f0 + 4] = o1;
  }
}

// ---------------------------------------------------------------------------
// kv kernel: per (head bh, S-chunk of 512 rows):
//   pkv[chunk][bh][f][d] = sum_s k'[s,f] * v[s,d]   (d=64 column = k_sum)
// RFF for k computed on the fly per 64-row subtile.
// ---------------------------------------------------------------------------
__global__ __launch_bounds__(256, 1) void kv_kernel(
    const float* __restrict__ kg, const float* __restrict__ vg,
    const float* __restrict__ rffW, const float* __restrict__ rffb,
    float* __restrict__ pkv)
{
  __shared__ float Kt[64][68];     // transposed k subtile [d][row]
  __shared__ float vs[64][68];     // v subtile [row][d]
  __shared__ float kps[64][268];   // k' subtile [row][f]
  const int bh    = blockIdx.x;    // 0..63
  const int chunk = blockIdx.y;    // 0..7
  const int b = bh >> 4, h = bh & 15;
  const int tid = threadIdx.x;
  const int fq = tid >> 3;         // f = fq*8..+7
  const int dq = tid & 7;          // d = dq*8..+7
  float acc2[8][8];
  float ksum8[8];
#pragma unroll
  for (int i = 0; i < 8; ++i) {
    ksum8[i] = 0.f;
#pragma unroll
    for (int j = 0; j < 8; ++j) acc2[i][j] = 0.f;
  }

  const int s_base = chunk * 512;
  for (int st = 0; st < 8; ++st) {
    const int s0 = s_base + st * 64;
    // stage k (transposed) and v subtiles
#pragma unroll
    for (int i = 0; i < 16; ++i) {
      int e = tid + i * 256;       // 0..4095
      int r = e >> 6, d = e & 63;
      size_t gbase = ((size_t)(b * S_LEN + s0 + r)) * DMODEL + h * KDIM;
      Kt[d][r] = kg[gbase + d];
      vs[r][d] = vg[gbase + d];
    }
    __syncthreads();
    rff_tile(Kt, kps, rffW, rffb, tid);
    __syncthreads();
    // accumulate kv over the 64 rows
    for (int s = 0; s < 64; ++s) {
      float4 a0 = *(const float4*)&kps[s][fq * 8];
      float4 a1 = *(const float4*)&kps[s][fq * 8 + 4];
      float4 v0 = *(const float4*)&vs[s][dq * 8];
      float4 v1 = *(const float4*)&vs[s][dq * 8 + 4];
      float av[8] = {a0.x, a0.y, a0.z, a0.w, a1.x, a1.y, a1.z, a1.w};
      float vv[8] = {v0.x, v0.y, v0.z, v0.w, v1.x, v1.y, v1.z, v1.w};
#pragma unroll
      for (int i = 0; i < 8; ++i) {
        ksum8[i] += av[i];
#pragma unroll
        for (int j = 0; j < 8; ++j)
          acc2[i][j] = fmaf(av[i], vv[j], acc2[i][j]);
      }
    }
    __syncthreads();
  }
  // ksum8 accumulated 8x (once per dq replica is same value; we summed per
  // subtile for ALL dq - every dq thread has the full chunk sum; dq==0 writes)
  size_t base = ((size_t)chunk * 64 + bh) * (size_t)(NF * 68);
#pragma unroll
  for (int i = 0; i < 8; ++i) {
    int f = fq * 8 + i;
    float4 o0 = {acc2[i][0], acc2[i][1], acc2[i][2], acc2[i][3]};
    float4 o1 = {acc2[i][4], acc2[i][5], acc2[i][6], acc2[i][7]};
    *(float4*)&pkv[base + (size_t)f * 68 + dq * 8]     = o0;
    *(float4*)&pkv[base + (size_t)f * 68 + dq * 8 + 4] = o1;
  }
  if (dq == 0) {
#pragma unroll
    for (int i = 0; i < 8; ++i)
      pkv[base + (size_t)(fq * 8 + i) * 68 + 64] = ksum8[i];
  }
}

// ---------------------------------------------------------------------------
// reduce 8 S-chunk partials -> kvb[bh][f][0..67] (col 64 = k_sum)
// ---------------------------------------------------------------------------
__global__ __launch_bounds__(256) void reduce_kv(
    const float* __restrict__ pkv, float* __restrict__ kvb, int n)
{
  int i = blockIdx.x * 256 + threadIdx.x;
  if (i >= n) return;
  float s = 0.f;
#pragma unroll
  for (int c = 0; c < 8; ++c) s += pkv[(size_t)c * n + i];
  kvb[i] = s;
}

// ---------------------------------------------------------------------------
// attn kernel: per (head bh, 64-row tile): q' on the fly, then
//   att[b,s,h*64+d] = (sum_f q'[s,f] kv[f,d]) / (sum_f q'[s,f] ksum[f] + eps)
// ---------------------------------------------------------------------------
__global__ __launch_bounds__(256, 1) void attn_kernel(
    const float* __restrict__ qg, const float* __restrict__ kvb,
    const float* __restrict__ rffW, const float* __restrict__ rffb,
    float* __restrict__ att)
{
  __shared__ float Qt[64][68];
  __shared__ float qps[64][268];
  __shared__ float ksums[NF];
  const int bh = blockIdx.x;      // 0..63
  const int rt = blockIdx.y;      // 0..63
  const int b = bh >> 4, h = bh & 15;
  const int tid = threadIdx.x;
  const int s0 = rt * 64;

#pragma unroll
  for (int i = 0; i < 16; ++i) {
    int e = tid + i * 256;
    int r = e >> 6, d = e & 63;
    Qt[d][r] = qg[((size_t)(b * S_LEN + s0 + r)) * DMODEL + h * KDIM + d];
  }
  ksums[tid] = kvb[((size_t)bh * NF + tid) * 68 + 64];
  __syncthreads();
  rff_tile(Qt, qps, rffW, rffb, tid);
  __syncthreads();

  const int r  = tid >> 2;        // row 0..63
  const int p  = tid & 3;
  const int d0 = p * 16;
  float acc[16];
#pragma unroll
  for (int j = 0; j < 16; ++j) acc[j] = 0.f;
  float den = 0.f;
  const float* kvrow = kvb + (size_t)bh * NF * 68;
  for (int f = 0; f < NF; ++f) {
    float qp = qps[r][f];
    den = fmaf(qp, ksums[f], den);
    const float4* kv4 = (const float4*)(kvrow + (size_t)f * 68 + d0);
#pragma unroll
    for (int jj = 0; jj < 4; ++jj) {
      float4 kk = kv4[jj];
      acc[jj * 4 + 0] = fmaf(qp, kk.x, acc[jj * 4 + 0]);
      acc[jj * 4 + 1] = fmaf(qp, kk.y, acc[jj * 4 + 1]);
      acc[jj * 4 + 2] = fmaf(qp, kk.z, acc[jj * 4 + 2]);
      acc[jj * 4 + 3] = fmaf(qp, kk.w, acc[jj * 4 + 3]);
    }
  }
  float inv = 1.0f / (den + 1e-6f);
  size_t obase = ((size_t)(b * S_LEN + s0 + r)) * DMODEL + h * KDIM + d0;
#pragma unroll
  for (int jj = 0; jj < 4; ++jj) {
    float4 o = {acc[jj*4+0] * inv, acc[jj*4+1] * inv,
                acc[jj*4+2] * inv, acc[jj*4+3] * inv};
    *(float4*)&att[obase + jj * 4] = o;
  }
}

// ---------------------------------------------------------------------------
// kernel_launch
// inputs: 0:x 1:Wq 2:bq 3:Wk 4:bk 5:Wv 6:bv 7:rff_W 8:rff_b 9:Wo 10:bo
// ws layout (floats): q[16.78M] k[16.78M] v[16.78M] kvb[1.11M] pkv[8.91M]
//   att reuses the k buffer (k fully consumed by kv_kernel before attn).
//   total = 60,358,656 floats = 230.2 MiB
// ---------------------------------------------------------------------------
extern "C" void kernel_launch(void* const* d_in, const int* in_sizes, int n_in,
                              void* d_out, int out_size, void* d_ws, size_t ws_size,
                              hipStream_t stream)
{
  const float* x    = (const float*)d_in[0];
  const float* Wq   = (const float*)d_in[1];
  const float* bq   = (const float*)d_in[2];
  const float* Wk   = (const float*)d_in[3];
  const float* bk   = (const float*)d_in[4];
  const float* Wv   = (const float*)d_in[5];
  const float* bv   = (const float*)d_in[6];
  const float* rffW = (const float*)d_in[7];
  const float* rffb = (const float*)d_in[8];
  const float* Wo   = (const float*)d_in[9];
  const float* bo   = (const float*)d_in[10];
  float* out = (float*)d_out;

  float* w = (float*)d_ws;
  const size_t QSZ = (size_t)NROWS * DMODEL;   // 16,777,216
  float* qb  = w;
  float* kb  = w + QSZ;
  float* vb  = w + 2 * QSZ;
  float* kvb = w + 3 * QSZ;                    // 64*256*68 = 1,114,112
  float* pkv = kvb + (size_t)64 * NF * 68;     // 8 * 1,114,112

  dim3 gemm_grid(DMODEL / 128, NROWS / 128);   // (8,128)
  gemm_bias_f32<<<gemm_grid, 256, 0, stream>>>(x, Wq, bq, qb, NROWS, DMODEL, DMODEL);
  gemm_bias_f32<<<gemm_grid, 256, 0, stream>>>(x, Wk, bk, kb, NROWS, DMODEL, DMODEL);
  gemm_bias_f32<<<gemm_grid, 256, 0, stream>>>(x, Wv, bv, vb, NROWS, DMODEL, DMODEL);

  kv_kernel<<<dim3(64, 8), 256, 0, stream>>>(kb, vb, rffW, rffb, pkv);

  int n = 64 * NF * 68;                        // 1,114,112
  reduce_kv<<<(n + 255) / 256, 256, 0, stream>>>(pkv, kvb, n);

  // att overwrites kb (k is no longer needed)
  attn_kernel<<<dim3(64, 64), 256, 0, stream>>>(qb, kvb, rffW, rffb, kb);

  gemm_bias_f32<<<gemm_grid, 256, 0, stream>>>(kb, Wo, bo, out, NROWS, DMODEL, DMODEL);
}

// Round 2
// 491.973 us; speedup vs baseline: 6.7489x; 6.7489x over previous
//
#include <hip/hip_runtime.h>
#include <hip/hip_bf16.h>
#include <math.h>

#define B_SZ    4
#define S_LEN   4096
#define DMODEL  1024
#define NH      16
#define KDIM    64
#define NF      256
#define NROWS   (B_SZ * S_LEN)          // 16384
#define RFF_SCALE 0.08838834764831845f  // sqrt(2/256)
#define NORM_Q    0.125f                // 1/sqrt(64)

typedef __attribute__((ext_vector_type(8))) short s8v;
typedef __attribute__((ext_vector_type(4))) float f4v;

static __device__ __forceinline__ unsigned short f2bf(float f) {
  unsigned u = __float_as_uint(f);
  unsigned r = (u + 0x7FFFu + ((u >> 16) & 1u)) >> 16;   // RNE
  return (unsigned short)r;
}

#define MFMA16(a, b, c) __builtin_amdgcn_mfma_f32_16x16x32_bf16((a), (b), (c), 0, 0, 0)

// ---------------------------------------------------------------------------
// cast x fp32 -> bf16, 8 elems/thread
// ---------------------------------------------------------------------------
__global__ __launch_bounds__(256) void cast_bf16_kernel(
    const float* __restrict__ src, unsigned short* __restrict__ dst, int n8)
{
  int i = blockIdx.x * 256 + threadIdx.x;
  if (i >= n8) return;
  const float* s = src + (size_t)i * 8;
  float4 a = *(const float4*)s;
  float4 b = *(const float4*)(s + 4);
  union { s8v v; unsigned short u[8]; } o;
  o.u[0]=f2bf(a.x); o.u[1]=f2bf(a.y); o.u[2]=f2bf(a.z); o.u[3]=f2bf(a.w);
  o.u[4]=f2bf(b.x); o.u[5]=f2bf(b.y); o.u[6]=f2bf(b.z); o.u[7]=f2bf(b.w);
  *(s8v*)(dst + (size_t)i * 8) = o.v;
}

// ---------------------------------------------------------------------------
// transpose+cast: W[1024][1024] fp32 -> WT[1024][1024] bf16 (WT[n][k]=W[k][n])
// ---------------------------------------------------------------------------
__global__ __launch_bounds__(256) void transpose_cast_kernel(
    const float* __restrict__ W, unsigned short* __restrict__ WT)
{
  __shared__ float t[32][33];
  const int k0 = blockIdx.y * 32, n0 = blockIdx.x * 32;
  const int c = threadIdx.x & 31, r4 = threadIdx.x >> 5;
#pragma unroll
  for (int i = 0; i < 4; ++i) {
    int row = r4 + i * 8;
    t[row][c] = W[(size_t)(k0 + row) * 1024 + n0 + c];
  }
  __syncthreads();
#pragma unroll
  for (int i = 0; i < 4; ++i) {
    int row = r4 + i * 8;
    WT[(size_t)(n0 + row) * 1024 + k0 + c] = f2bf(t[c][row]);
  }
}

// rffW[64][256] fp32 -> rffWT[256][64] bf16, NORM folded in
__global__ __launch_bounds__(256) void prep_rff_kernel(
    const float* __restrict__ rffW, unsigned short* __restrict__ rffWT)
{
  int i = blockIdx.x * 256 + threadIdx.x;   // 16384
  int f = i >> 6, d = i & 63;
  rffWT[(size_t)f * 64 + d] = f2bf(rffW[(size_t)d * 256 + f] * NORM_Q);
}

// ---------------------------------------------------------------------------
// bf16 MFMA GEMM: C[M,N] = A[M,K] @ BT[N,K]^T + bias
// 128x128 tile, BK=32, 4 waves each 64x64 (4x4 mfma tiles).
// QKV-fused variant: selects BT/bias/out by global n-block.
// ---------------------------------------------------------------------------
template <int OUT_BF16, int QKV_FUSED>
__global__ __launch_bounds__(256) void gemm_bt_kernel(
    const unsigned short* __restrict__ A,
    const unsigned short* __restrict__ BT0,
    const unsigned short* __restrict__ BT1,
    const unsigned short* __restrict__ BT2,
    const float* __restrict__ bias0, const float* __restrict__ bias1,
    const float* __restrict__ bias2,
    void* __restrict__ out0, void* __restrict__ out1, void* __restrict__ out2,
    int M, int N, int K)   // N = per-output N (1024)
{
  __shared__ __align__(16) unsigned short As[128 * 40];
  __shared__ __align__(16) unsigned short Bs[128 * 40];
  const int tid = threadIdx.x;
  const int lane = tid & 63, wave = tid >> 6;
  const int m0 = blockIdx.y * 128;
  int ngl = blockIdx.x * 128;   // global n (may span q/k/v)
  const unsigned short* BT = BT0;
  const float* bias = bias0;
  void* outp = out0;
  if (QKV_FUSED) {
    int which = ngl >> 10;
    if (which == 1) { BT = BT1; bias = bias1; outp = out1; }
    else if (which == 2) { BT = BT2; bias = bias2; outp = out2; }
    ngl &= 1023;
  }
  const int n0 = ngl;
  const int wm = (wave >> 1) * 64, wn = (wave & 1) * 64;
  const int col = lane & 15, quad = lane >> 4;

  f4v acc[4][4];
  const f4v zz = {0.f, 0.f, 0.f, 0.f};
#pragma unroll
  for (int i = 0; i < 4; ++i)
#pragma unroll
    for (int j = 0; j < 4; ++j) acc[i][j] = zz;

  for (int k0 = 0; k0 < K; k0 += 32) {
#pragma unroll
    for (int i = 0; i < 2; ++i) {
      int c = tid + i * 256;          // 0..511
      int row = c >> 2, ch = c & 3;   // 4 x 16B chunks per 32-elem row
      *(s8v*)&As[row * 40 + ch * 8] =
          *(const s8v*)(A + (size_t)(m0 + row) * K + k0 + ch * 8);
      *(s8v*)&Bs[row * 40 + ch * 8] =
          *(const s8v*)(BT + (size_t)(n0 + row) * K + k0 + ch * 8);
    }
    __syncthreads();
    s8v af[4], bf[4];
#pragma unroll
    for (int t = 0; t < 4; ++t) {
      af[t] = *(const s8v*)&As[(wm + t * 16 + col) * 40 + quad * 8];
      bf[t] = *(const s8v*)&Bs[(wn + t * 16 + col) * 40 + quad * 8];
    }
#pragma unroll
    for (int i = 0; i < 4; ++i)
#pragma unroll
      for (int j = 0; j < 4; ++j)
        acc[i][j] = MFMA16(af[i], bf[j], acc[i][j]);
    __syncthreads();
  }
  // epilogue: C row = quad*4+r (A-side), col = lane&15 (B-side)
#pragma unroll
  for (int i = 0; i < 4; ++i) {
#pragma unroll
    for (int j = 0; j < 4; ++j) {
      int n = n0 + wn + j * 16 + col;
      float bv = bias[n];
#pragma unroll
      for (int r = 0; r < 4; ++r) {
        int m = m0 + wm + i * 16 + quad * 4 + r;
        float v = acc[i][j][r] + bv;
        if (OUT_BF16)
          ((unsigned short*)outp)[(size_t)m * N + n] = f2bf(v);
        else
          ((float*)outp)[(size_t)m * N + n] = v;
      }
    }
  }
}

// ---------------------------------------------------------------------------
// kv kernel (MFMA): per (bh, s-chunk of 512):
//   pkv[chunk][bh][f][d<80] = sum_s k'[s,f]*vext[s,d],  vext col 64 = 1 (ksum)
// k' computed on the fly: proj-MFMA(k_tile @ rffWT^T) -> cos -> bf16 LDS.
// ---------------------------------------------------------------------------
__global__ __launch_bounds__(256, 1) void kv_kernel(
    const unsigned short* __restrict__ kg, const unsigned short* __restrict__ vg,
    const unsigned short* __restrict__ rffWT, const float* __restrict__ rffb,
    float* __restrict__ pkv)
{
  __shared__ __align__(16) unsigned short kt[64 * 72];    // k tile [s][d]
  __shared__ __align__(16) unsigned short vT[80 * 72];    // v^T [d][s], row64=1
  __shared__ __align__(16) unsigned short wl[256 * 72];   // rffWT [f][d]
  __shared__ __align__(16) unsigned short kps[256 * 72];  // k'^T [f][s]
  __shared__ float rb[256];
  const int bh = blockIdx.x, chunk = blockIdx.y;
  const int b = bh >> 4, h = bh & 15;
  const int tid = threadIdx.x;
  const int lane = tid & 63, wave = tid >> 6;
  const int col = lane & 15, quad = lane >> 4;

  // stage rffWT + rffb once
  for (int c = tid; c < 2048; c += 256) {
    int f = c >> 3, ch = c & 7;
    *(s8v*)&wl[f * 72 + ch * 8] = *(const s8v*)(rffWT + (size_t)f * 64 + ch * 8);
  }
  rb[tid] = rffb[tid];

  f4v kvacc[4][5];
  const f4v zz = {0.f, 0.f, 0.f, 0.f};
#pragma unroll
  for (int i = 0; i < 4; ++i)
#pragma unroll
    for (int j = 0; j < 5; ++j) kvacc[i][j] = zz;

  for (int st = 0; st < 8; ++st) {
    const int s0 = chunk * 512 + st * 64;
    __syncthreads();
    // stage k tile [64][72]
#pragma unroll
    for (int i = 0; i < 2; ++i) {
      int c = tid + i * 256;          // 512 chunks
      int r = c >> 3, ch = c & 7;
      *(s8v*)&kt[r * 72 + ch * 8] =
          *(const s8v*)(kg + ((size_t)(b * S_LEN + s0 + r)) * DMODEL + h * KDIM + ch * 8);
    }
    // stage v^T [80][72]: rows 0..63 = v transposed, row 64 = 1.0, 65..79 = 0
#pragma unroll
    for (int i = 0; i < 2; ++i) {
      int c = tid + i * 256;
      int s = c & 63, ch = c >> 6;    // ch 0..7
      union { s8v v; unsigned short u[8]; } vv;
      vv.v = *(const s8v*)(vg + ((size_t)(b * S_LEN + s0 + s)) * DMODEL + h * KDIM + ch * 8);
#pragma unroll
      for (int j = 0; j < 8; ++j) vT[(ch * 8 + j) * 72 + s] = vv.u[j];
    }
    for (int e = tid; e < 1024; e += 256) {       // rows 64..79
      int r = 64 + (e >> 6), s = e & 63;
      vT[r * 72 + s] = (r == 64) ? (unsigned short)0x3F80 : (unsigned short)0;
    }
    __syncthreads();
    // proj MFMA: [64 s] x [256 f], K=64. wave handles f-range wave*64.
    {
      f4v p[4][4];
#pragma unroll
      for (int i = 0; i < 4; ++i)
#pragma unroll
        for (int j = 0; j < 4; ++j) p[i][j] = zz;
#pragma unroll
      for (int ks = 0; ks < 64; ks += 32) {
        s8v af[4], bf[4];
#pragma unroll
        for (int t = 0; t < 4; ++t) {
          af[t] = *(const s8v*)&kt[(t * 16 + col) * 72 + ks + quad * 8];
          bf[t] = *(const s8v*)&wl[(wave * 64 + t * 16 + col) * 72 + ks + quad * 8];
        }
#pragma unroll
        for (int i = 0; i < 4; ++i)
#pragma unroll
          for (int j = 0; j < 4; ++j) p[i][j] = MFMA16(af[i], bf[j], p[i][j]);
      }
      // cos epilogue -> kps[f][s]
#pragma unroll
      for (int j = 0; j < 4; ++j) {
        int f = wave * 64 + j * 16 + col;
        float bfv = rb[f];
#pragma unroll
        for (int i = 0; i < 4; ++i)
#pragma unroll
          for (int r = 0; r < 4; ++r) {
            int s = i * 16 + quad * 4 + r;
            kps[f * 72 + s] = f2bf(__cosf(p[i][j][r] + bfv) * RFF_SCALE);
          }
      }
    }
    __syncthreads();
    // kv MFMA: A = kps [256 f][72 s], B = vT [80 d][72 s]; wave f-range wave*64
#pragma unroll
    for (int ks = 0; ks < 64; ks += 32) {
      s8v af[4], bf[5];
#pragma unroll
      for (int t = 0; t < 4; ++t)
        af[t] = *(const s8v*)&kps[(wave * 64 + t * 16 + col) * 72 + ks + quad * 8];
#pragma unroll
      for (int t = 0; t < 5; ++t)
        bf[t] = *(const s8v*)&vT[(t * 16 + col) * 72 + ks + quad * 8];
#pragma unroll
      for (int i = 0; i < 4; ++i)
#pragma unroll
        for (int j = 0; j < 5; ++j)
          kvacc[i][j] = MFMA16(af[i], bf[j], kvacc[i][j]);
    }
  }
  // write pkv fp32: row (f) = wave*64 + i*16 + quad*4 + r; col d = j*16 + col
  const size_t base = ((size_t)(chunk * 64 + bh)) * NF * 80;
#pragma unroll
  for (int i = 0; i < 4; ++i)
#pragma unroll
    for (int r = 0; r < 4; ++r) {
      int f = wave * 64 + i * 16 + quad * 4 + r;
#pragma unroll
      for (int j = 0; j < 5; ++j)
        pkv[base + (size_t)f * 80 + j * 16 + col] = kvacc[i][j][r];
    }
}

// ---------------------------------------------------------------------------
// reduce 8 chunk partials, transpose -> kvT bf16 [bh][80 d][256 f]
// ---------------------------------------------------------------------------
__global__ __launch_bounds__(256) void reduce_kv_kernel(
    const float* __restrict__ pkv, unsigned short* __restrict__ kvT)
{
  __shared__ unsigned short lt[80 * 256];
  const int bh = blockIdx.x;
  for (int e = threadIdx.x; e < NF * 80; e += 256) {
    float s = 0.f;
#pragma unroll
    for (int c = 0; c < 8; ++c)
      s += pkv[((size_t)(c * 64 + bh)) * NF * 80 + e];
    int f = e / 80, d = e - f * 80;
    lt[d * 256 + f] = f2bf(s);
  }
  __syncthreads();
  for (int o = threadIdx.x; o < 80 * NF; o += 256)
    kvT[(size_t)bh * 80 * NF + o] = lt[o];
}

// ---------------------------------------------------------------------------
// attn kernel (MFMA): per (bh, rgroup of 4 x 64 rows):
//   q' = cos(q @ rffWT^T + b)*scale ; num[64][80] = q' @ kvT^T ;
//   att = num[:, :64] / (num[:,64] + eps)  -> bf16
// ---------------------------------------------------------------------------
__global__ __launch_bounds__(256, 1) void attn_kernel(
    const unsigned short* __restrict__ qg, const unsigned short* __restrict__ kvTg,
    const unsigned short* __restrict__ rffWT, const float* __restrict__ rffb,
    unsigned short* __restrict__ att)
{
  __shared__ __align__(16) unsigned short qt[64 * 72];     // q tile [s][d]
  __shared__ __align__(16) unsigned short wl[256 * 72];    // rffWT [f][d]
  __shared__ __align__(16) unsigned short qps[64 * 264];   // q' [s][f]
  __shared__ __align__(16) unsigned short kvs[80 * 264];   // kvT [d][f]
  __shared__ float rb[256];
  const int bh = blockIdx.x;
  const int b = bh >> 4, h = bh & 15;
  const int tid = threadIdx.x;
  const int lane = tid & 63, wave = tid >> 6;
  const int col = lane & 15, quad = lane >> 4;
  const f4v zz = {0.f, 0.f, 0.f, 0.f};

  for (int c = tid; c < 2048; c += 256) {
    int f = c >> 3, ch = c & 7;
    *(s8v*)&wl[f * 72 + ch * 8] = *(const s8v*)(rffWT + (size_t)f * 64 + ch * 8);
  }
  for (int c = tid; c < 2560; c += 256) {
    int d = c >> 5, ch = c & 31;
    *(s8v*)&kvs[d * 264 + ch * 8] =
        *(const s8v*)(kvTg + (size_t)bh * 80 * NF + d * 256 + ch * 8);
  }
  rb[tid] = rffb[tid];

  for (int it = 0; it < 4; ++it) {
    const int s0 = (blockIdx.y * 4 + it) * 64;
    __syncthreads();
#pragma unroll
    for (int i = 0; i < 2; ++i) {
      int c = tid + i * 256;
      int r = c >> 3, ch = c & 7;
      *(s8v*)&qt[r * 72 + ch * 8] =
          *(const s8v*)(qg + ((size_t)(b * S_LEN + s0 + r)) * DMODEL + h * KDIM + ch * 8);
    }
    __syncthreads();
    // proj
    {
      f4v p[4][4];
#pragma unroll
      for (int i = 0; i < 4; ++i)
#pragma unroll
        for (int j = 0; j < 4; ++j) p[i][j] = zz;
#pragma unroll
      for (int ks = 0; ks < 64; ks += 32) {
        s8v af[4], bf[4];
#pragma unroll
        for (int t = 0; t < 4; ++t) {
          af[t] = *(const s8v*)&qt[(t * 16 + col) * 72 + ks + quad * 8];
          bf[t] = *(const s8v*)&wl[(wave * 64 + t * 16 + col) * 72 + ks + quad * 8];
        }
#pragma unroll
        for (int i = 0; i < 4; ++i)
#pragma unroll
          for (int j = 0; j < 4; ++j) p[i][j] = MFMA16(af[i], bf[j], p[i][j]);
      }
#pragma unroll
      for (int j = 0; j < 4; ++j) {
        int f = wave * 64 + j * 16 + col;
        float bfv = rb[f];
#pragma unroll
        for (int i = 0; i < 4; ++i)
#pragma unroll
          for (int r = 0; r < 4; ++r) {
            int s = i * 16 + quad * 4 + r;
            qps[s * 264 + f] = f2bf(__cosf(p[i][j][r] + bfv) * RFF_SCALE);
          }
      }
    }
    __syncthreads();
    // num: A = qps [64][264], B = kvs [80][264], K=256; wave -> m-tile `wave`
    f4v acc[5];
#pragma unroll
    for (int j = 0; j < 5; ++j) acc[j] = zz;
    for (int k0 = 0; k0 < 256; k0 += 32) {
      s8v af = *(const s8v*)&qps[(wave * 16 + col) * 264 + k0 + quad * 8];
      s8v bf[5];
#pragma unroll
      for (int t = 0; t < 5; ++t)
        bf[t] = *(const s8v*)&kvs[(t * 16 + col) * 264 + k0 + quad * 8];
#pragma unroll
      for (int j = 0; j < 5; ++j) acc[j] = MFMA16(af, bf[j], acc[j]);
    }
    // den = tile 4 col 0, broadcast within quad
    float inv[4];
#pragma unroll
    for (int r = 0; r < 4; ++r) {
      float den = __shfl(acc[4][r], lane & 48);
      inv[r] = 1.0f / (den + 1e-6f);
    }
#pragma unroll
    for (int r = 0; r < 4; ++r) {
      int m = s0 + wave * 16 + quad * 4 + r;
      size_t obase = ((size_t)(b * S_LEN + m)) * DMODEL + h * KDIM;
#pragma unroll
      for (int j = 0; j < 4; ++j)
        att[obase + j * 16 + col] = f2bf(acc[j][r] * inv[r]);
    }
  }
}

// ---------------------------------------------------------------------------
// kernel_launch. inputs: 0:x 1:Wq 2:bq 3:Wk 4:bk 5:Wv 6:bv 7:rff_W 8:rff_b 9:Wo 10:bo
// ws (bytes): xb 33.55M | WqT/WkT/WvT/WoT 2.1M x4 | rffWT 33K |
//             qb/kb/vb 33.55M x3 | pkv 41.9M | kvT 2.6M ; att reuses kb.
// ---------------------------------------------------------------------------
extern "C" void kernel_launch(void* const* d_in, const int* in_sizes, int n_in,
                              void* d_out, int out_size, void* d_ws, size_t ws_size,
                              hipStream_t stream)
{
  const float* x    = (const float*)d_in[0];
  const float* Wq   = (const float*)d_in[1];
  const float* bq   = (const float*)d_in[2];
  const float* Wk   = (const float*)d_in[3];
  const float* bk   = (const float*)d_in[4];
  const float* Wv   = (const float*)d_in[5];
  const float* bv   = (const float*)d_in[6];
  const float* rffW = (const float*)d_in[7];
  const float* rffb = (const float*)d_in[8];
  const float* Wo   = (const float*)d_in[9];
  const float* bo   = (const float*)d_in[10];
  float* out = (float*)d_out;

  char* w = (char*)d_ws;
  const size_t XB = (size_t)NROWS * DMODEL * 2;     // 33,554,432
  const size_t WT = (size_t)DMODEL * DMODEL * 2;    // 2,097,152
  unsigned short* xb   = (unsigned short*)(w);
  unsigned short* WqT  = (unsigned short*)(w + XB);
  unsigned short* WkT  = (unsigned short*)(w + XB + WT);
  unsigned short* WvT  = (unsigned short*)(w + XB + 2 * WT);
  unsigned short* WoT  = (unsigned short*)(w + XB + 3 * WT);
  unsigned short* rWT  = (unsigned short*)(w + XB + 4 * WT);
  char* p = w + XB + 4 * WT + 65536;
  unsigned short* qb = (unsigned short*)(p);
  unsigned short* kb = (unsigned short*)(p + XB);
  unsigned short* vb = (unsigned short*)(p + 2 * XB);
  float* pkv         = (float*)(p + 3 * XB);
  unsigned short* kvT = (unsigned short*)(p + 3 * XB + (size_t)8 * 64 * NF * 80 * 4);
  unsigned short* att = kb;   // kb consumed before attn writes

  cast_bf16_kernel<<<NROWS * DMODEL / 8 / 256, 256, 0, stream>>>(x, xb, NROWS * DMODEL / 8);
  dim3 tg(32, 32);
  transpose_cast_kernel<<<tg, 256, 0, stream>>>(Wq, WqT);
  transpose_cast_kernel<<<tg, 256, 0, stream>>>(Wk, WkT);
  transpose_cast_kernel<<<tg, 256, 0, stream>>>(Wv, WvT);
  transpose_cast_kernel<<<tg, 256, 0, stream>>>(Wo, WoT);
  prep_rff_kernel<<<64, 256, 0, stream>>>(rffW, rWT);

  gemm_bt_kernel<1, 1><<<dim3(24, 128), 256, 0, stream>>>(
      xb, WqT, WkT, WvT, bq, bk, bv, qb, kb, vb, NROWS, DMODEL, DMODEL);

  kv_kernel<<<dim3(64, 8), 256, 0, stream>>>(kb, vb, rWT, rffb, pkv);
  reduce_kv_kernel<<<64, 256, 0, stream>>>(pkv, kvT);
  attn_kernel<<<dim3(64, 16), 256, 0, stream>>>(qb, kvT, rWT, rffb, att);

  gemm_bt_kernel<0, 0><<<dim3(8, 128), 256, 0, stream>>>(
      att, WoT, nullptr, nullptr, bo, nullptr, nullptr, out, nullptr, nullptr,
      NROWS, DMODEL, DMODEL);
}

// Round 3
// 486.586 us; speedup vs baseline: 6.8236x; 1.0111x over previous
//
#include <hip/hip_runtime.h>
#include <hip/hip_bf16.h>
#include <math.h>

#define B_SZ    4
#define S_LEN   4096
#define DMODEL  1024
#define NH      16
#define KDIM    64
#define NF      256
#define NROWS   (B_SZ * S_LEN)          // 16384
#define RFF_SCALE 0.08838834764831845f  // sqrt(2/256)
#define NORM_Q    0.125f                // 1/sqrt(64)

typedef __attribute__((ext_vector_type(8))) short s8v;
typedef __attribute__((ext_vector_type(4))) float f4v;

static __device__ __forceinline__ unsigned short f2bf(float f) {
  unsigned u = __float_as_uint(f);
  unsigned r = (u + 0x7FFFu + ((u >> 16) & 1u)) >> 16;   // RNE
  return (unsigned short)r;
}

#define MFMA16(a, b, c) __builtin_amdgcn_mfma_f32_16x16x32_bf16((a), (b), (c), 0, 0, 0)

// async global->LDS, 16B per lane. LDS dest is wave-uniform base + lane*16.
__device__ __forceinline__ void glds16(const void* g, void* l) {
  __builtin_amdgcn_global_load_lds(
      (const __attribute__((address_space(1))) void*)g,
      (__attribute__((address_space(3))) void*)l, 16, 0, 0);
}

// ---------------------------------------------------------------------------
// cast x fp32 -> bf16
// ---------------------------------------------------------------------------
__global__ __launch_bounds__(256) void cast_bf16_kernel(
    const float* __restrict__ src, unsigned short* __restrict__ dst, int n8)
{
  int i = blockIdx.x * 256 + threadIdx.x;
  if (i >= n8) return;
  const float* s = src + (size_t)i * 8;
  float4 a = *(const float4*)s;
  float4 b = *(const float4*)(s + 4);
  union { s8v v; unsigned short u[8]; } o;
  o.u[0]=f2bf(a.x); o.u[1]=f2bf(a.y); o.u[2]=f2bf(a.z); o.u[3]=f2bf(a.w);
  o.u[4]=f2bf(b.x); o.u[5]=f2bf(b.y); o.u[6]=f2bf(b.z); o.u[7]=f2bf(b.w);
  *(s8v*)(dst + (size_t)i * 8) = o.v;
}

// ---------------------------------------------------------------------------
// transpose+cast: W[1024][1024] fp32 -> WT[1024][1024] bf16
// ---------------------------------------------------------------------------
__global__ __launch_bounds__(256) void transpose_cast_kernel(
    const float* __restrict__ W, unsigned short* __restrict__ WT)
{
  __shared__ float t[32][33];
  const int k0 = blockIdx.y * 32, n0 = blockIdx.x * 32;
  const int c = threadIdx.x & 31, r4 = threadIdx.x >> 5;
#pragma unroll
  for (int i = 0; i < 4; ++i) {
    int row = r4 + i * 8;
    t[row][c] = W[(size_t)(k0 + row) * 1024 + n0 + c];
  }
  __syncthreads();
#pragma unroll
  for (int i = 0; i < 4; ++i) {
    int row = r4 + i * 8;
    WT[(size_t)(n0 + row) * 1024 + k0 + c] = f2bf(t[c][row]);
  }
}

// rffW[64][256] fp32 -> rffWT[256][64] bf16, NORM folded in
__global__ __launch_bounds__(256) void prep_rff_kernel(
    const float* __restrict__ rffW, unsigned short* __restrict__ rffWT)
{
  int i = blockIdx.x * 256 + threadIdx.x;   // 16384
  int f = i >> 6, d = i & 63;
  rffWT[(size_t)f * 64 + d] = f2bf(rffW[(size_t)d * 256 + f] * NORM_Q);
}

// ---------------------------------------------------------------------------
// bf16 MFMA GEMM (m97 structure): C[M,N] = A[M,K] @ BT[N,K]^T + bias
// 128x128 tile, BK=32, unpadded LDS, global_load_lds dwordx4 staging.
// ---------------------------------------------------------------------------
template <int OUT_BF16, int QKV_FUSED>
__global__ __launch_bounds__(256) void gemm_bt_kernel(
    const unsigned short* __restrict__ A,
    const unsigned short* __restrict__ BT0,
    const unsigned short* __restrict__ BT1,
    const unsigned short* __restrict__ BT2,
    const float* __restrict__ bias0, const float* __restrict__ bias1,
    const float* __restrict__ bias2,
    void* __restrict__ out0, void* __restrict__ out1, void* __restrict__ out2,
    int M, int N, int K)
{
  __shared__ __align__(16) unsigned short As[128 * 32];
  __shared__ __align__(16) unsigned short Bs[128 * 32];
  const int tid = threadIdx.x;
  const int lane = tid & 63, wave = tid >> 6;
  const int m0 = blockIdx.y * 128;
  int ngl = blockIdx.x * 128;
  const unsigned short* BT = BT0;
  const float* bias = bias0;
  void* outp = out0;
  if (QKV_FUSED) {
    int which = ngl >> 10;
    if (which == 1) { BT = BT1; bias = bias1; outp = out1; }
    else if (which == 2) { BT = BT2; bias = bias2; outp = out2; }
    ngl &= 1023;
  }
  const int n0 = ngl;
  const int wm = (wave >> 1) * 64, wn = (wave & 1) * 64;
  const int col = lane & 15, quad = lane >> 4;

  f4v acc[4][4];
  const f4v zz = {0.f, 0.f, 0.f, 0.f};
#pragma unroll
  for (int i = 0; i < 4; ++i)
#pragma unroll
    for (int j = 0; j < 4; ++j) acc[i][j] = zz;

  for (int k0 = 0; k0 < K; k0 += 32) {
#pragma unroll
    for (int i = 0; i < 2; ++i) {
      int cb = i * 256 + wave * 64;          // wave-uniform chunk base
      int c  = cb + lane;
      int row = c >> 2, ch = c & 3;
      glds16(A  + (size_t)(m0 + row) * K + k0 + ch * 8, &As[cb * 8]);
      glds16(BT + (size_t)(n0 + row) * K + k0 + ch * 8, &Bs[cb * 8]);
    }
    __syncthreads();
    s8v af[4], bf[4];
#pragma unroll
    for (int t = 0; t < 4; ++t) {
      af[t] = *(const s8v*)&As[(wm + t * 16 + col) * 32 + quad * 8];
      bf[t] = *(const s8v*)&Bs[(wn + t * 16 + col) * 32 + quad * 8];
    }
#pragma unroll
    for (int i = 0; i < 4; ++i)
#pragma unroll
      for (int j = 0; j < 4; ++j)
        acc[i][j] = MFMA16(af[i], bf[j], acc[i][j]);
    __syncthreads();
  }
#pragma unroll
  for (int i = 0; i < 4; ++i) {
#pragma unroll
    for (int j = 0; j < 4; ++j) {
      int n = n0 + wn + j * 16 + col;
      float bv = bias[n];
#pragma unroll
      for (int r = 0; r < 4; ++r) {
        int m = m0 + wm + i * 16 + quad * 4 + r;
        float v = acc[i][j][r] + bv;
        if (OUT_BF16)
          ((unsigned short*)outp)[(size_t)m * N + n] = f2bf(v);
        else
          ((float*)outp)[(size_t)m * N + n] = v;
      }
    }
  }
}

// ---------------------------------------------------------------------------
// kv kernel: grid (64 bh, 16 chunks of 256 rows).
//   pkv[chunk][bh][f][d<80] = sum_s k'[s,f]*vext[s,d], vext col 64 = 1.
// rffW B-frags in registers; k A-frags straight from global; LDS = vT + kps.
// ---------------------------------------------------------------------------
__global__ __launch_bounds__(256) void kv_kernel(
    const unsigned short* __restrict__ kg, const unsigned short* __restrict__ vg,
    const unsigned short* __restrict__ rffWT, const float* __restrict__ rffb,
    float* __restrict__ pkv)
{
  __shared__ __align__(16) unsigned short vT[80 * 72];    // v^T [d][s], row64=1
  __shared__ __align__(16) unsigned short kps[256 * 72];  // k'^T [f][s]
  const int bh = blockIdx.x, chunk = blockIdx.y;
  const int b = bh >> 4, h = bh & 15;
  const int tid = threadIdx.x;
  const int lane = tid & 63, wave = tid >> 6;
  const int col = lane & 15, quad = lane >> 4;
  const f4v zz = {0.f, 0.f, 0.f, 0.f};

  // rffW B-fragments (wave's f-range = wave*64..+63) + bias, in registers
  s8v wf[2][4];
  float bfv[4];
#pragma unroll
  for (int ks = 0; ks < 2; ++ks)
#pragma unroll
    for (int t = 0; t < 4; ++t)
      wf[ks][t] = *(const s8v*)(rffWT +
          (size_t)(wave * 64 + t * 16 + col) * 64 + ks * 32 + quad * 8);
#pragma unroll
  for (int j = 0; j < 4; ++j) bfv[j] = rffb[wave * 64 + j * 16 + col];

  // constant vT rows 64..79 (ones row + zeros)
  for (int e = tid; e < 1024; e += 256) {
    int r = 64 + (e >> 6), s = e & 63;
    vT[r * 72 + s] = (r == 64) ? (unsigned short)0x3F80 : (unsigned short)0;
  }

  f4v kvacc[4][5];
#pragma unroll
  for (int i = 0; i < 4; ++i)
#pragma unroll
    for (int j = 0; j < 5; ++j) kvacc[i][j] = zz;

  for (int st = 0; st < 4; ++st) {
    const int s0 = chunk * 256 + st * 64;
    __syncthreads();   // previous kv-MFMA done reading vT/kps
    // stage v^T rows 0..63
#pragma unroll
    for (int i = 0; i < 2; ++i) {
      int c = tid + i * 256;
      int s = c & 63, ch = c >> 6;
      union { s8v v; unsigned short u[8]; } vv;
      vv.v = *(const s8v*)(vg + ((size_t)(b * S_LEN + s0 + s)) * DMODEL + h * KDIM + ch * 8);
#pragma unroll
      for (int j = 0; j < 8; ++j) vT[(ch * 8 + j) * 72 + s] = vv.u[j];
    }
    // proj MFMA: A from global k, B from registers
    f4v p[4][4];
#pragma unroll
    for (int i = 0; i < 4; ++i)
#pragma unroll
      for (int j = 0; j < 4; ++j) p[i][j] = zz;
#pragma unroll
    for (int ks = 0; ks < 2; ++ks) {
      s8v af[4];
#pragma unroll
      for (int t = 0; t < 4; ++t)
        af[t] = *(const s8v*)(kg +
            ((size_t)(b * S_LEN + s0 + t * 16 + col)) * DMODEL + h * KDIM + ks * 32 + quad * 8);
#pragma unroll
      for (int i = 0; i < 4; ++i)
#pragma unroll
        for (int j = 0; j < 4; ++j) p[i][j] = MFMA16(af[i], wf[ks][j], p[i][j]);
    }
    // cos epilogue -> kps[f][s]
#pragma unroll
    for (int j = 0; j < 4; ++j) {
      int f = wave * 64 + j * 16 + col;
#pragma unroll
      for (int i = 0; i < 4; ++i)
#pragma unroll
        for (int r = 0; r < 4; ++r) {
          int s = i * 16 + quad * 4 + r;
          kps[f * 72 + s] = f2bf(__cosf(p[i][j][r] + bfv[j]) * RFF_SCALE);
        }
    }
    __syncthreads();   // kps + vT visible
    // kv MFMA: A = kps (wave's f-range), B = vT
#pragma unroll
    for (int ks = 0; ks < 2; ++ks) {
      s8v af[4], bf[5];
#pragma unroll
      for (int t = 0; t < 4; ++t)
        af[t] = *(const s8v*)&kps[(wave * 64 + t * 16 + col) * 72 + ks * 32 + quad * 8];
#pragma unroll
      for (int t = 0; t < 5; ++t)
        bf[t] = *(const s8v*)&vT[(t * 16 + col) * 72 + ks * 32 + quad * 8];
#pragma unroll
      for (int i = 0; i < 4; ++i)
#pragma unroll
        for (int j = 0; j < 5; ++j)
          kvacc[i][j] = MFMA16(af[i], bf[j], kvacc[i][j]);
    }
  }
  const size_t base = ((size_t)(chunk * 64 + bh)) * NF * 80;
#pragma unroll
  for (int i = 0; i < 4; ++i)
#pragma unroll
    for (int r = 0; r < 4; ++r) {
      int f = wave * 64 + i * 16 + quad * 4 + r;
#pragma unroll
      for (int j = 0; j < 5; ++j)
        pkv[base + (size_t)f * 80 + j * 16 + col] = kvacc[i][j][r];
    }
}

// ---------------------------------------------------------------------------
// reduce 16 chunk partials, transpose -> kvT bf16 [bh][80 d][256 f]
// ---------------------------------------------------------------------------
__global__ __launch_bounds__(256) void reduce_kv_kernel(
    const float* __restrict__ pkv, unsigned short* __restrict__ kvT)
{
  __shared__ unsigned short lt[80 * 256];
  const int bh = blockIdx.x;
  for (int e = threadIdx.x; e < NF * 80; e += 256) {
    float s = 0.f;
#pragma unroll
    for (int c = 0; c < 16; ++c)
      s += pkv[((size_t)(c * 64 + bh)) * NF * 80 + e];
    int f = e / 80, d = e - f * 80;
    lt[d * 256 + f] = f2bf(s);
  }
  __syncthreads();
  for (int o = threadIdx.x; o < 80 * NF; o += 256)
    kvT[(size_t)bh * 80 * NF + o] = lt[o];
}

// ---------------------------------------------------------------------------
// attn kernel: grid (64 bh, 16), 4 x 64-row tiles per block.
//   q' = cos(q @ rffWT^T + b)*scale; num = q' @ kvT^T; att = num/(den+eps)
// LDS = qps + kvs only (76 KB -> 2 blocks/CU).
// ---------------------------------------------------------------------------
__global__ __launch_bounds__(256) void attn_kernel(
    const unsigned short* __restrict__ qg, const unsigned short* __restrict__ kvTg,
    const unsigned short* __restrict__ rffWT, const float* __restrict__ rffb,
    unsigned short* __restrict__ att)
{
  __shared__ __align__(16) unsigned short qps[64 * 264];   // q' [s][f]
  __shared__ __align__(16) unsigned short kvs[80 * 264];   // kvT [d][f]
  const int bh = blockIdx.x;
  const int b = bh >> 4, h = bh & 15;
  const int tid = threadIdx.x;
  const int lane = tid & 63, wave = tid >> 6;
  const int col = lane & 15, quad = lane >> 4;
  const f4v zz = {0.f, 0.f, 0.f, 0.f};

  s8v wf[2][4];
  float bfv[4];
#pragma unroll
  for (int ks = 0; ks < 2; ++ks)
#pragma unroll
    for (int t = 0; t < 4; ++t)
      wf[ks][t] = *(const s8v*)(rffWT +
          (size_t)(wave * 64 + t * 16 + col) * 64 + ks * 32 + quad * 8);
#pragma unroll
  for (int j = 0; j < 4; ++j) bfv[j] = rffb[wave * 64 + j * 16 + col];

  // stage kv [80][256] -> kvs stride 264
  for (int c = tid; c < 2560; c += 256) {
    int d = c >> 5, ch = c & 31;
    *(s8v*)&kvs[d * 264 + ch * 8] =
        *(const s8v*)(kvTg + (size_t)bh * 80 * NF + d * 256 + ch * 8);
  }

  for (int it = 0; it < 4; ++it) {
    const int s0 = (blockIdx.y * 4 + it) * 64;
    // proj: A from global q, B from registers
    f4v p[4][4];
#pragma unroll
    for (int i = 0; i < 4; ++i)
#pragma unroll
      for (int j = 0; j < 4; ++j) p[i][j] = zz;
#pragma unroll
    for (int ks = 0; ks < 2; ++ks) {
      s8v af[4];
#pragma unroll
      for (int t = 0; t < 4; ++t)
        af[t] = *(const s8v*)(qg +
            ((size_t)(b * S_LEN + s0 + t * 16 + col)) * DMODEL + h * KDIM + ks * 32 + quad * 8);
#pragma unroll
      for (int i = 0; i < 4; ++i)
#pragma unroll
        for (int j = 0; j < 4; ++j) p[i][j] = MFMA16(af[i], wf[ks][j], p[i][j]);
    }
    __syncthreads();   // previous num-MFMA done reading qps (also fences kvs stage)
#pragma unroll
    for (int j = 0; j < 4; ++j) {
      int f = wave * 64 + j * 16 + col;
#pragma unroll
      for (int i = 0; i < 4; ++i)
#pragma unroll
        for (int r = 0; r < 4; ++r) {
          int s = i * 16 + quad * 4 + r;
          qps[s * 264 + f] = f2bf(__cosf(p[i][j][r] + bfv[j]) * RFF_SCALE);
        }
    }
    __syncthreads();
    // num: A = qps rows wave*16..+15, B = kvs, K=256
    f4v acc[5];
#pragma unroll
    for (int j = 0; j < 5; ++j) acc[j] = zz;
#pragma unroll
    for (int k0 = 0; k0 < 256; k0 += 32) {
      s8v af = *(const s8v*)&qps[(wave * 16 + col) * 264 + k0 + quad * 8];
      s8v bf[5];
#pragma unroll
      for (int t = 0; t < 5; ++t)
        bf[t] = *(const s8v*)&kvs[(t * 16 + col) * 264 + k0 + quad * 8];
#pragma unroll
      for (int j = 0; j < 5; ++j) acc[j] = MFMA16(af, bf[j], acc[j]);
    }
    float inv[4];
#pragma unroll
    for (int r = 0; r < 4; ++r) {
      float den = __shfl(acc[4][r], lane & 48);
      inv[r] = 1.0f / (den + 1e-6f);
    }
#pragma unroll
    for (int r = 0; r < 4; ++r) {
      int m = s0 + wave * 16 + quad * 4 + r;
      size_t obase = ((size_t)(b * S_LEN + m)) * DMODEL + h * KDIM;
#pragma unroll
      for (int j = 0; j < 4; ++j)
        att[obase + j * 16 + col] = f2bf(acc[j][r] * inv[r]);
    }
  }
}

// ---------------------------------------------------------------------------
// kernel_launch. inputs: 0:x 1:Wq 2:bq 3:Wk 4:bk 5:Wv 6:bv 7:rff_W 8:rff_b 9:Wo 10:bo
// ---------------------------------------------------------------------------
extern "C" void kernel_launch(void* const* d_in, const int* in_sizes, int n_in,
                              void* d_out, int out_size, void* d_ws, size_t ws_size,
                              hipStream_t stream)
{
  const float* x    = (const float*)d_in[0];
  const float* Wq   = (const float*)d_in[1];
  const float* bq   = (const float*)d_in[2];
  const float* Wk   = (const float*)d_in[3];
  const float* bk   = (const float*)d_in[4];
  const float* Wv   = (const float*)d_in[5];
  const float* bv   = (const float*)d_in[6];
  const float* rffW = (const float*)d_in[7];
  const float* rffb = (const float*)d_in[8];
  const float* Wo   = (const float*)d_in[9];
  const float* bo   = (const float*)d_in[10];
  float* out = (float*)d_out;

  char* w = (char*)d_ws;
  const size_t XB = (size_t)NROWS * DMODEL * 2;     // 33,554,432
  const size_t WT = (size_t)DMODEL * DMODEL * 2;    // 2,097,152
  unsigned short* xb   = (unsigned short*)(w);
  unsigned short* WqT  = (unsigned short*)(w + XB);
  unsigned short* WkT  = (unsigned short*)(w + XB + WT);
  unsigned short* WvT  = (unsigned short*)(w + XB + 2 * WT);
  unsigned short* WoT  = (unsigned short*)(w + XB + 3 * WT);
  unsigned short* rWT  = (unsigned short*)(w + XB + 4 * WT);
  char* p = w + XB + 4 * WT + 65536;
  unsigned short* qb = (unsigned short*)(p);
  unsigned short* kb = (unsigned short*)(p + XB);
  unsigned short* vb = (unsigned short*)(p + 2 * XB);
  float* pkv         = (float*)(p + 3 * XB);
  unsigned short* kvT = (unsigned short*)(p + 3 * XB + (size_t)16 * 64 * NF * 80 * 4);
  unsigned short* att = kb;   // kb consumed before attn writes

  cast_bf16_kernel<<<NROWS * DMODEL / 8 / 256, 256, 0, stream>>>(x, xb, NROWS * DMODEL / 8);
  dim3 tg(32, 32);
  transpose_cast_kernel<<<tg, 256, 0, stream>>>(Wq, WqT);
  transpose_cast_kernel<<<tg, 256, 0, stream>>>(Wk, WkT);
  transpose_cast_kernel<<<tg, 256, 0, stream>>>(Wv, WvT);
  transpose_cast_kernel<<<tg, 256, 0, stream>>>(Wo, WoT);
  prep_rff_kernel<<<64, 256, 0, stream>>>(rffW, rWT);

  gemm_bt_kernel<1, 1><<<dim3(24, 128), 256, 0, stream>>>(
      xb, WqT, WkT, WvT, bq, bk, bv, qb, kb, vb, NROWS, DMODEL, DMODEL);

  kv_kernel<<<dim3(64, 16), 256, 0, stream>>>(kb, vb, rWT, rffb, pkv);
  reduce_kv_kernel<<<64, 256, 0, stream>>>(pkv, kvT);
  attn_kernel<<<dim3(64, 16), 256, 0, stream>>>(qb, kvT, rWT, rffb, att);

  gemm_bt_kernel<0, 0><<<dim3(8, 128), 256, 0, stream>>>(
      att, WoT, nullptr, nullptr, bo, nullptr, nullptr, out, nullptr, nullptr,
      NROWS, DMODEL, DMODEL);
}